// Round 2
// baseline (2621.608 us; speedup 1.0000x reference)
//
// HOPE forward on MI355X (gfx950).
// Pipeline:
//   q,k = proj(x) [split-bf16 MFMA GEMM, elu+1 on k, fused tiled hi/lo out]
//   v = proj(x) [fp32 out, transposed+tiled by convB]
//   scores = (q @ k^T) * decay_mask  [mask epilogue, strictly-upper tiles skipped]
//   fast = scores @ v [K-banded: upper scores are structural zeros]
//   fastp = fast @ Wo + bo ; h = LN(x + fastp)
//   4x CMS: t = gelu(h@W1+b1) [fused tiled out]; y = t@W2+b2; h = LN(h+y)
//   out = h @ Wh + bh
// All GEMMs: fp32 emulated as Ah*Bh + Ah*Bl + Al*Bh (bf16 hi/lo split),
// operands in tiled layout [blk128][kchunk][row128][8] so global_load_lds
// staging is contiguous and LDS fragment reads are conflict-free.
// Workspace use: ~355 MB.

#include <hip/hip_runtime.h>
#include <cstdint>

typedef __bf16 bf16;
typedef bf16 bf16x8 __attribute__((ext_vector_type(8)));
typedef bf16 bf16x4 __attribute__((ext_vector_type(4)));
typedef float f32x4 __attribute__((ext_vector_type(4)));
typedef __attribute__((address_space(1))) uint32_t gu32;
typedef __attribute__((address_space(3))) uint32_t lu32;

#define DEV static __device__ __forceinline__

DEV void gl_lds16(const bf16* g, bf16* l) {
  __builtin_amdgcn_global_load_lds((const gu32*)g, (lu32*)l, 16, 0, 0);
}

// ---------------- decay power table ----------------
__global__ void k_pow(const float* __restrict__ dp, float* __restrict__ powd) {
  const int i = blockIdx.x * 256 + threadIdx.x;
  if (i < 2048) {
    const float decay = 1.0f / (1.0f + expf(-dp[0]));
    powd[i] = powf(decay, (float)i);
  }
}

// ---------------- convert fp32 [M][K] (row-major) -> tiled hi/lo ----------------
// out[((mblk*Kc + kc)*128 + row)*8 + j] ; block covers 128 rows x 64 k
__global__ __launch_bounds__(256) void k_convA(const float* __restrict__ src,
                                               bf16* __restrict__ dh,
                                               bf16* __restrict__ dl, int K) {
  const int Kc = K >> 3;
  const int kc0 = blockIdx.x * 8;
  const int mblk = blockIdx.y;
  const int t = threadIdx.x;
  const int kcl = t & 7;
  const int r0 = t >> 3;
#pragma unroll
  for (int ri = 0; ri < 4; ++ri) {
    const int row = ri * 32 + r0;
    const float* p = src + (size_t)(mblk * 128 + row) * K + (size_t)(kc0 + kcl) * 8;
    const float4 a = *(const float4*)p;
    const float4 b = *(const float4*)(p + 4);
    const float v[8] = {a.x, a.y, a.z, a.w, b.x, b.y, b.z, b.w};
    bf16x8 h, l;
#pragma unroll
    for (int j = 0; j < 8; ++j) {
      const bf16 hj = (bf16)v[j];
      h[j] = hj;
      l[j] = (bf16)(v[j] - (float)hj);
    }
    const size_t off = ((size_t)(mblk * Kc + kc0 + kcl) * 128 + row) * 8;
    *(bf16x8*)(dh + off) = h;
    *(bf16x8*)(dl + off) = l;
  }
}

// ---------------- convert fp32 [K][N] (N contiguous) -> tiled hi/lo of B^T [N][K] ----------------
__global__ __launch_bounds__(256) void k_convB(const float* __restrict__ src,
                                               bf16* __restrict__ dh,
                                               bf16* __restrict__ dl, int K, int N,
                                               long long sbat, long long dbat) {
  src += (long long)blockIdx.z * sbat;
  dh += (long long)blockIdx.z * dbat;
  dl += (long long)blockIdx.z * dbat;
  const int Kc = K >> 3;
  const int kc0 = blockIdx.x * 8;
  const int nblk = blockIdx.y;
  const int t = threadIdx.x;
  const int c = t & 127;
  const int h2 = t >> 7;
#pragma unroll
  for (int it = 0; it < 4; ++it) {
    const int kcl = it * 2 + h2;
    const int kb = (kc0 + kcl) * 8;
    float v[8];
#pragma unroll
    for (int j = 0; j < 8; ++j) v[j] = src[(size_t)(kb + j) * N + nblk * 128 + c];
    bf16x8 h, l;
#pragma unroll
    for (int j = 0; j < 8; ++j) {
      const bf16 hj = (bf16)v[j];
      h[j] = hj;
      l[j] = (bf16)(v[j] - (float)hj);
    }
    const size_t off = ((size_t)(nblk * Kc + kc0 + kcl) * 128 + c) * 8;
    *(bf16x8*)(dh + off) = h;
    *(bf16x8*)(dl + off) = l;
  }
}

// ---------------- split-bf16 GEMM: C = A * B^T (+epilogue) ----------------
// A tiled [M][K], B tiled from B^T [N][K]. 128x128 tile, BK=32, 4 waves.
// EPI: 0=bias, 1=elu(x)+1 after bias, 2=exact gelu after bias, 3=decay mask (scores)
// TOUT: write result as tiled hi/lo (A-layout for the next GEMM) instead of fp32 C.
// kband: if >0, clamp K-tiles to (mblk+1)*kband (causal banding for fast GEMM).
template <int EPI, bool TOUT>
__global__ __launch_bounds__(256, 2) void k_gemm(
    const bf16* __restrict__ Ah, const bf16* __restrict__ Al,
    const bf16* __restrict__ Bh, const bf16* __restrict__ Bl,
    float* __restrict__ C, bf16* __restrict__ Dh, bf16* __restrict__ Dl,
    const float* __restrict__ bias, const float* __restrict__ powd,
    int N, int K, int kband,
    long long abat, long long bbat, long long cbat) {
  const int mblk = blockIdx.x;  // grid.x = M tiles: consecutive blocks share B panel
  const int nblk = blockIdx.y;
  if (EPI == 3 && nblk > mblk) return;  // strictly-upper causal tiles: mask==0, never read

  Ah += (long long)blockIdx.z * abat;
  Al += (long long)blockIdx.z * abat;
  Bh += (long long)blockIdx.z * bbat;
  Bl += (long long)blockIdx.z * bbat;
  C += (long long)blockIdx.z * cbat;
  Dh += (long long)blockIdx.z * cbat;
  Dl += (long long)blockIdx.z * cbat;

  const int tid = threadIdx.x;
  const int lane = tid & 63;
  const int wave = tid >> 6;
  const int wm = (wave >> 1) * 64;
  const int wn = (wave & 1) * 64;
  const int kg = lane >> 4;
  const int rr = lane & 15;

  __shared__ __align__(16) bf16 sAh[4096], sAl[4096], sBh[4096], sBl[4096];

  const size_t aBase = (size_t)mblk * K * 128 + (size_t)tid * 8;
  const size_t bBase = (size_t)nblk * K * 128 + (size_t)tid * 8;

  f32x4 acc[4][4];
  const f32x4 zero = {0.0f, 0.0f, 0.0f, 0.0f};
#pragma unroll
  for (int m = 0; m < 4; ++m)
#pragma unroll
    for (int n = 0; n < 4; ++n) acc[m][n] = zero;

  int nk = K >> 5;
  if (kband) {
    const int cap = (mblk + 1) * kband;
    nk = nk < cap ? nk : cap;
  }
  for (int kt = 0; kt < nk; ++kt) {
    const size_t ga = aBase + (size_t)kt * 4096;
    const size_t gb = bBase + (size_t)kt * 4096;
    gl_lds16(Ah + ga, sAh + tid * 8);
    gl_lds16(Ah + ga + 2048, sAh + 2048 + tid * 8);
    gl_lds16(Al + ga, sAl + tid * 8);
    gl_lds16(Al + ga + 2048, sAl + 2048 + tid * 8);
    gl_lds16(Bh + gb, sBh + tid * 8);
    gl_lds16(Bh + gb + 2048, sBh + 2048 + tid * 8);
    gl_lds16(Bl + gb, sBl + tid * 8);
    gl_lds16(Bl + gb + 2048, sBl + 2048 + tid * 8);
    __syncthreads();

    bf16x8 fah[4], fal[4], fbh[4], fbl[4];
#pragma unroll
    for (int m = 0; m < 4; ++m) {
      const int off = (kg * 128 + wm + m * 16 + rr) * 8;
      fah[m] = *(const bf16x8*)(sAh + off);
      fal[m] = *(const bf16x8*)(sAl + off);
    }
#pragma unroll
    for (int n = 0; n < 4; ++n) {
      const int off = (kg * 128 + wn + n * 16 + rr) * 8;
      fbh[n] = *(const bf16x8*)(sBh + off);
      fbl[n] = *(const bf16x8*)(sBl + off);
    }
#pragma unroll
    for (int m = 0; m < 4; ++m)
#pragma unroll
      for (int n = 0; n < 4; ++n) {
        acc[m][n] = __builtin_amdgcn_mfma_f32_16x16x32_bf16(fah[m], fbh[n], acc[m][n], 0, 0, 0);
        acc[m][n] = __builtin_amdgcn_mfma_f32_16x16x32_bf16(fah[m], fbl[n], acc[m][n], 0, 0, 0);
        acc[m][n] = __builtin_amdgcn_mfma_f32_16x16x32_bf16(fal[m], fbh[n], acc[m][n], 0, 0, 0);
      }
    __syncthreads();
  }

  // epilogue: C/D layout col = lane&15, row = (lane>>4)*4 + j (verified mapping)
  const int Kc2 = N >> 3;
#pragma unroll
  for (int n = 0; n < 4; ++n) {
    const int gcol = nblk * 128 + wn + n * 16 + rr;
    const float bv = bias ? bias[gcol] : 0.0f;
    const size_t tb = ((size_t)(mblk * Kc2 + (gcol >> 3)) * 128) * 8 + (gcol & 7);
#pragma unroll
    for (int m = 0; m < 4; ++m) {
#pragma unroll
      for (int j = 0; j < 4; ++j) {
        const int r = wm + kg * 4 + m * 16 + j;
        float x = acc[m][n][j] + bv;
        if (EPI == 1) x = (x > 0.0f) ? x + 1.0f : expf(x);
        if (EPI == 2) x = 0.5f * x * (1.0f + erff(x * 0.70710678118654752f));
        if (EPI == 3) {
          const int e = (mblk * 128 + r) - gcol - 1;
          x = (e >= 0) ? x * powd[e] : 0.0f;
        }
        if (!TOUT) {
          C[(size_t)(mblk * 128 + r) * N + gcol] = x;
        } else {
          const bf16 h = (bf16)x;
          Dh[tb + (size_t)r * 8] = h;
          Dl[tb + (size_t)r * 8] = (bf16)(x - (float)h);
        }
      }
    }
  }
}

// ---------------- fused residual + LayerNorm, emits fp32 + tiled hi/lo ----------------
__global__ __launch_bounds__(256) void k_ln(const float* x1, const float* x2,
                                            const float* g, const float* be,
                                            float* out, bf16* th, bf16* tl) {
  const int row = blockIdx.x;
  const int t = threadIdx.x;
  const int lane = t & 63;
  const int wave = t >> 6;
  const float4 a = *(const float4*)(x1 + (size_t)row * 1024 + t * 4);
  const float4 b = *(const float4*)(x2 + (size_t)row * 1024 + t * 4);
  float v[4] = {a.x + b.x, a.y + b.y, a.z + b.z, a.w + b.w};
  __shared__ float red[4];
  float s = v[0] + v[1] + v[2] + v[3];
#pragma unroll
  for (int o = 1; o < 64; o <<= 1) s += __shfl_xor(s, o);
  if (lane == 0) red[wave] = s;
  __syncthreads();
  s = red[0] + red[1] + red[2] + red[3];
  const float mean = s * (1.0f / 1024.0f);
  float q = 0.0f;
#pragma unroll
  for (int j = 0; j < 4; ++j) {
    const float d = v[j] - mean;
    q += d * d;
  }
#pragma unroll
  for (int o = 1; o < 64; o <<= 1) q += __shfl_xor(q, o);
  __syncthreads();
  if (lane == 0) red[wave] = q;
  __syncthreads();
  q = red[0] + red[1] + red[2] + red[3];
  const float rstd = rsqrtf(q * (1.0f / 1024.0f) + 1e-5f);
  const int cc = t * 4;
  float y[4];
#pragma unroll
  for (int j = 0; j < 4; ++j) y[j] = (v[j] - mean) * rstd * g[cc + j] + be[cc + j];
  const float4 o4 = {y[0], y[1], y[2], y[3]};
  *(float4*)(out + (size_t)row * 1024 + cc) = o4;
  // tiled hi/lo write (D=1024 -> Kc=128)
  const int mblk = row >> 7, r = row & 127, kc = t >> 1, j0 = (t & 1) * 4;
  const size_t off = ((size_t)(mblk * 128 + kc) * 128 + r) * 8 + j0;
  bf16x4 hh, ll;
#pragma unroll
  for (int j = 0; j < 4; ++j) {
    const bf16 hj = (bf16)y[j];
    hh[j] = hj;
    ll[j] = (bf16)(y[j] - (float)hj);
  }
  *(bf16x4*)(th + off) = hh;
  *(bf16x4*)(tl + off) = ll;
}

// ---------------- launch ----------------
extern "C" void kernel_launch(void* const* d_in, const int* in_sizes, int n_in,
                              void* d_out, int out_size, void* d_ws, size_t ws_size,
                              hipStream_t stream) {
  const float* x = (const float*)d_in[0];
  const float* Wq = (const float*)d_in[1];
  const float* bq = (const float*)d_in[2];
  const float* Wk = (const float*)d_in[3];
  const float* bk = (const float*)d_in[4];
  const float* Wv = (const float*)d_in[5];
  const float* bv = (const float*)d_in[6];
  const float* Wo = (const float*)d_in[7];
  const float* bo = (const float*)d_in[8];
  const float* dp = (const float*)d_in[9];
  const float* gf = (const float*)d_in[10];
  const float* bfv = (const float*)d_in[11];
  const float* W1 = (const float*)d_in[12];
  const float* b1 = (const float*)d_in[13];
  const float* W2 = (const float*)d_in[14];
  const float* b2 = (const float*)d_in[15];
  const float* gc = (const float*)d_in[16];
  const float* bc = (const float*)d_in[17];
  const float* Wh = (const float*)d_in[18];
  const float* bh = (const float*)d_in[19];
  float* out = (float*)d_out;

  char* w = (char*)d_ws;
  size_t o = 0;
  auto alloc = [&](size_t bytes) -> void* {
    void* p = w + o;
    o += (bytes + 255) & ~(size_t)255;
    return p;
  };
  const size_t MD = (size_t)4096 * 1024;   // [B*S][D] elements
  float* powd = (float*)alloc(2048 * 4);
  bf16* XAh = (bf16*)alloc(MD * 2);
  bf16* XAl = (bf16*)alloc(MD * 2);
  bf16* Wqh = (bf16*)alloc((size_t)1024 * 1024 * 2);
  bf16* Wql = (bf16*)alloc((size_t)1024 * 1024 * 2);
  bf16* Wkh = (bf16*)alloc((size_t)1024 * 1024 * 2);
  bf16* Wkl = (bf16*)alloc((size_t)1024 * 1024 * 2);
  bf16* Wvh = (bf16*)alloc((size_t)1024 * 1024 * 2);
  bf16* Wvl = (bf16*)alloc((size_t)1024 * 1024 * 2);
  bf16* Woh = (bf16*)alloc((size_t)1024 * 1024 * 2);
  bf16* Wol = (bf16*)alloc((size_t)1024 * 1024 * 2);
  float* vf = (float*)alloc(MD * 4);
  bf16* vTh = (bf16*)alloc(MD * 2);  // 2 batches x tiled [1024][2048]
  bf16* vTl = (bf16*)alloc(MD * 2);
  bf16* SCh = (bf16*)alloc((size_t)2 * 2048 * 2048 * 2);  // scores tiled
  bf16* SCl = (bf16*)alloc((size_t)2 * 2048 * 2048 * 2);
  bf16* AHh = (bf16*)alloc((size_t)4096 * 4096 * 2);  // q-tiled / fast-tiled / gelu-tiled
  bf16* AHl = (bf16*)alloc((size_t)4096 * 4096 * 2);
  bf16* BHh = (bf16*)alloc((size_t)32000 * 1024 * 2);  // k-tiled / W1/W2/Wh-tiled
  bf16* BHl = (bf16*)alloc((size_t)32000 * 1024 * 2);
  float* hf = (float*)alloc(MD * 4);
  float* t1 = (float*)alloc(MD * 4);
  float* t2 = (float*)alloc(MD * 4);
  bf16* hAh = (bf16*)alloc(MD * 2);
  bf16* hAl = (bf16*)alloc(MD * 2);

  const long long SD = 2048LL * 1024;
  const long long SS = 2048LL * 2048;
  float* nullf = nullptr;
  bf16* nullb = nullptr;

  k_pow<<<8, 256, 0, stream>>>(dp, powd);

  // --- projections (q,k fused to tiled; v to fp32 for transpose) ---
  k_convA<<<dim3(16, 32), 256, 0, stream>>>(x, XAh, XAl, 1024);
  k_convB<<<dim3(16, 8), 256, 0, stream>>>(Wq, Wqh, Wql, 1024, 1024, 0, 0);
  k_convB<<<dim3(16, 8), 256, 0, stream>>>(Wk, Wkh, Wkl, 1024, 1024, 0, 0);
  k_convB<<<dim3(16, 8), 256, 0, stream>>>(Wv, Wvh, Wvl, 1024, 1024, 0, 0);
  k_convB<<<dim3(16, 8), 256, 0, stream>>>(Wo, Woh, Wol, 1024, 1024, 0, 0);
  k_gemm<0, true><<<dim3(32, 8), 256, 0, stream>>>(XAh, XAl, Wqh, Wql, nullf, AHh, AHl,
                                                   bq, nullptr, 1024, 1024, 0, 0, 0, 0);
  k_gemm<1, true><<<dim3(32, 8), 256, 0, stream>>>(XAh, XAl, Wkh, Wkl, nullf, BHh, BHl,
                                                   bk, nullptr, 1024, 1024, 0, 0, 0, 0);
  k_gemm<0, false><<<dim3(32, 8), 256, 0, stream>>>(XAh, XAl, Wvh, Wvl, vf, nullb, nullb,
                                                    bv, nullptr, 1024, 1024, 0, 0, 0, 0);
  k_convB<<<dim3(32, 8, 2), 256, 0, stream>>>(vf, vTh, vTl, 2048, 1024, SD, SD);

  // --- decayed linear attention ---
  // scores = (q k^T) * mask, strictly-upper tiles skipped; output tiled for fast GEMM
  k_gemm<3, true><<<dim3(16, 16, 2), 256, 0, stream>>>(AHh, AHl, BHh, BHl, nullf, SCh, SCl,
                                                       nullptr, powd, 2048, 1024, 0, SD, SD, SS);
  // fast = scores @ v, K banded to the causal lower triangle
  k_gemm<0, true><<<dim3(16, 8, 2), 256, 0, stream>>>(SCh, SCl, vTh, vTl, nullf, AHh, AHl,
                                                      nullptr, nullptr, 1024, 2048, 4, SS, SD, SD);
  k_gemm<0, false><<<dim3(32, 8), 256, 0, stream>>>(AHh, AHl, Woh, Wol, t2, nullb, nullb,
                                                    bo, nullptr, 1024, 1024, 0, 0, 0, 0);
  k_ln<<<4096, 256, 0, stream>>>(x, t2, gf, bfv, hf, hAh, hAl);

  // --- CMS stack ---
  for (int l = 0; l < 4; ++l) {
    k_convB<<<dim3(16, 32), 256, 0, stream>>>(W1 + (size_t)l * 1024 * 4096, BHh, BHl, 1024, 4096, 0, 0);
    k_gemm<2, true><<<dim3(32, 32), 256, 0, stream>>>(hAh, hAl, BHh, BHl, nullf, AHh, AHl,
                                                      b1 + l * 4096, nullptr, 4096, 1024, 0, 0, 0, 0);
    k_convB<<<dim3(64, 8), 256, 0, stream>>>(W2 + (size_t)l * 4096 * 1024, BHh, BHl, 4096, 1024, 0, 0);
    k_gemm<0, false><<<dim3(32, 8), 256, 0, stream>>>(AHh, AHl, BHh, BHl, t1, nullb, nullb,
                                                      b2 + l * 1024, nullptr, 1024, 4096, 0, 0, 0, 0);
    k_ln<<<4096, 256, 0, stream>>>(hf, t1, gc + l * 1024, bc + l * 1024, hf, hAh, hAl);
  }

  // --- LM head ---
  k_convB<<<dim3(16, 250), 256, 0, stream>>>(Wh, BHh, BHl, 1024, 32000, 0, 0);
  k_gemm<0, false><<<dim3(32, 250), 256, 0, stream>>>(hAh, hAl, BHh, BHl, out, nullb, nullb,
                                                      bh, nullptr, 32000, 1024, 0, 0, 0, 0);
}

// Round 3
// 2459.821 us; speedup vs baseline: 1.0658x; 1.0658x over previous
//
// HOPE forward on MI355X (gfx950).
//   qkv = x@[Wq|Wk|Wv] (one merged GEMM; q,k -> tiled hi/lo, elu+1 on k; v -> fp32)
//   scores = (q @ k^T) * decay_mask  [strictly-upper tiles skipped]
//   fast = scores @ v [K-banded]
//   fastp = fast @ Wo (split-K=2 partials) ; h = LN(x + sum(parts) + bo)
//   4x CMS: t = gelu(h@W1+b1) [tiled out]; y = t@W2 (split-K=4 partials);
//           h = LN(h + sum(parts) + b2)
//   out = h @ Wh + bh
// GEMMs: fp32 emulated as Ah*Bh + Ah*Bl + Al*Bh (bf16 hi/lo split); operands in
// tiled layout [blk128][kchunk][row128][8] (contiguous global_load_lds staging,
// conflict-free LDS fragment reads). XCD-chunked block swizzle for grids>=768.
// Workspace: ~327 MB (attention scratch overlaid on CMS/head tile buffers).

#include <hip/hip_runtime.h>
#include <cstdint>

typedef __bf16 bf16;
typedef bf16 bf16x8 __attribute__((ext_vector_type(8)));
typedef bf16 bf16x4 __attribute__((ext_vector_type(4)));
typedef float f32x4 __attribute__((ext_vector_type(4)));
typedef __attribute__((address_space(1))) uint32_t gu32;
typedef __attribute__((address_space(3))) uint32_t lu32;

#define DEV static __device__ __forceinline__

DEV void gl_lds16(const bf16* g, bf16* l) {
  __builtin_amdgcn_global_load_lds((const gu32*)g, (lu32*)l, 16, 0, 0);
}

// ---------------- decay power table ----------------
__global__ void k_pow(const float* __restrict__ dp, float* __restrict__ powd) {
  const int i = blockIdx.x * 256 + threadIdx.x;
  if (i < 2048) {
    const float decay = 1.0f / (1.0f + expf(-dp[0]));
    powd[i] = powf(decay, (float)i);
  }
}

// ---------------- convert fp32 [M][K] (row-major) -> tiled hi/lo ----------------
__global__ __launch_bounds__(256) void k_convA(const float* __restrict__ src,
                                               bf16* __restrict__ dh,
                                               bf16* __restrict__ dl, int K) {
  const int Kc = K >> 3;
  const int kc0 = blockIdx.x * 8;
  const int mblk = blockIdx.y;
  const int t = threadIdx.x;
  const int kcl = t & 7;
  const int r0 = t >> 3;
#pragma unroll
  for (int ri = 0; ri < 4; ++ri) {
    const int row = ri * 32 + r0;
    const float* p = src + (size_t)(mblk * 128 + row) * K + (size_t)(kc0 + kcl) * 8;
    const float4 a = *(const float4*)p;
    const float4 b = *(const float4*)(p + 4);
    const float v[8] = {a.x, a.y, a.z, a.w, b.x, b.y, b.z, b.w};
    bf16x8 h, l;
#pragma unroll
    for (int j = 0; j < 8; ++j) {
      const bf16 hj = (bf16)v[j];
      h[j] = hj;
      l[j] = (bf16)(v[j] - (float)hj);
    }
    const size_t off = ((size_t)(mblk * Kc + kc0 + kcl) * 128 + row) * 8;
    *(bf16x8*)(dh + off) = h;
    *(bf16x8*)(dl + off) = l;
  }
}

// ------- convert fp32 [K][N] (N contiguous) -> tiled hi/lo of B^T [N][K] -------
__global__ __launch_bounds__(256) void k_convB(const float* __restrict__ src,
                                               bf16* __restrict__ dh,
                                               bf16* __restrict__ dl, int K, int N,
                                               long long sbat, long long dbat) {
  src += (long long)blockIdx.z * sbat;
  dh += (long long)blockIdx.z * dbat;
  dl += (long long)blockIdx.z * dbat;
  const int Kc = K >> 3;
  const int kc0 = blockIdx.x * 8;
  const int nblk = blockIdx.y;
  const int t = threadIdx.x;
  const int c = t & 127;
  const int h2 = t >> 7;
#pragma unroll
  for (int it = 0; it < 4; ++it) {
    const int kcl = it * 2 + h2;
    const int kb = (kc0 + kcl) * 8;
    float v[8];
#pragma unroll
    for (int j = 0; j < 8; ++j) v[j] = src[(size_t)(kb + j) * N + nblk * 128 + c];
    bf16x8 h, l;
#pragma unroll
    for (int j = 0; j < 8; ++j) {
      const bf16 hj = (bf16)v[j];
      h[j] = hj;
      l[j] = (bf16)(v[j] - (float)hj);
    }
    const size_t off = ((size_t)(nblk * Kc + kc0 + kcl) * 128 + c) * 8;
    *(bf16x8*)(dh + off) = h;
    *(bf16x8*)(dl + off) = l;
  }
}

// ---------------- split-bf16 GEMM: C = A * B^T (+epilogue) ----------------
// EPI: 0=bias, 2=exact gelu, 3=decay mask (scores), 4=merged qkv
// TOUT: write tiled hi/lo (next GEMM's A operand) instead of fp32 C.
// SPLITK: blockIdx.z = K-slice; partial fp32 written at C + z*cbat (no bias).
// kband>0: clamp K-tiles to (mblk+1)*kband (causal band for fast GEMM).
template <int EPI, bool TOUT, bool SPLITK>
__global__ __launch_bounds__(256, 2) void k_gemm(
    const bf16* __restrict__ Ah, const bf16* __restrict__ Al,
    const bf16* __restrict__ Bh, const bf16* __restrict__ Bl,
    float* __restrict__ C, bf16* __restrict__ Dh, bf16* __restrict__ Dl,
    bf16* __restrict__ Dh2, bf16* __restrict__ Dl2,
    const float* __restrict__ bias, const float* __restrict__ bias2,
    const float* __restrict__ bias3, const float* __restrict__ powd,
    int N, int K, int kband,
    long long abat, long long bbat, long long cbat) {
  int mblk = blockIdx.x;
  int nblk = blockIdx.y;
  const int nwg = (int)(gridDim.x * gridDim.y);
  if (nwg >= 768) {
    // XCD-chunked bijective swizzle (m204): XCD i owns a contiguous tile range.
    int id = (int)(blockIdx.y * gridDim.x + blockIdx.x);
    const int q = nwg >> 3, r = nwg & 7;
    const int xcd = id & 7, rank = id >> 3;
    id = (xcd < r ? xcd * (q + 1) : r * (q + 1) + (xcd - r) * q) + rank;
    mblk = id % (int)gridDim.x;
    nblk = id / (int)gridDim.x;
  }
  if (EPI == 3 && nblk > mblk) return;  // strictly-upper causal tiles: mask==0

  if (SPLITK) {
    C += (long long)blockIdx.z * cbat;
  } else {
    Ah += (long long)blockIdx.z * abat;
    Al += (long long)blockIdx.z * abat;
    Bh += (long long)blockIdx.z * bbat;
    Bl += (long long)blockIdx.z * bbat;
    C += (long long)blockIdx.z * cbat;
    Dh += (long long)blockIdx.z * cbat;
    Dl += (long long)blockIdx.z * cbat;
  }

  const int tid = threadIdx.x;
  const int lane = tid & 63;
  const int wave = tid >> 6;
  const int wm = (wave >> 1) * 64;
  const int wn = (wave & 1) * 64;
  const int kg = lane >> 4;
  const int rr = lane & 15;

  __shared__ __align__(16) bf16 sAh[4096], sAl[4096], sBh[4096], sBl[4096];

  const size_t aBase = (size_t)mblk * K * 128 + (size_t)tid * 8;
  const size_t bBase = (size_t)nblk * K * 128 + (size_t)tid * 8;

  f32x4 acc[4][4];
  const f32x4 zero = {0.0f, 0.0f, 0.0f, 0.0f};
#pragma unroll
  for (int m = 0; m < 4; ++m)
#pragma unroll
    for (int n = 0; n < 4; ++n) acc[m][n] = zero;

  int kt0 = 0;
  int nk = K >> 5;
  if (SPLITK) {
    const int per = nk / (int)gridDim.z;
    kt0 = (int)blockIdx.z * per;
    nk = kt0 + per;
  }
  if (kband) {
    const int cap = (mblk + 1) * kband;
    nk = nk < cap ? nk : cap;
  }
  for (int kt = kt0; kt < nk; ++kt) {
    const size_t ga = aBase + (size_t)kt * 4096;
    const size_t gb = bBase + (size_t)kt * 4096;
    gl_lds16(Ah + ga, sAh + tid * 8);
    gl_lds16(Ah + ga + 2048, sAh + 2048 + tid * 8);
    gl_lds16(Al + ga, sAl + tid * 8);
    gl_lds16(Al + ga + 2048, sAl + 2048 + tid * 8);
    gl_lds16(Bh + gb, sBh + tid * 8);
    gl_lds16(Bh + gb + 2048, sBh + 2048 + tid * 8);
    gl_lds16(Bl + gb, sBl + tid * 8);
    gl_lds16(Bl + gb + 2048, sBl + 2048 + tid * 8);
    __syncthreads();

    bf16x8 fah[4], fal[4], fbh[4], fbl[4];
#pragma unroll
    for (int m = 0; m < 4; ++m) {
      const int off = (kg * 128 + wm + m * 16 + rr) * 8;
      fah[m] = *(const bf16x8*)(sAh + off);
      fal[m] = *(const bf16x8*)(sAl + off);
    }
#pragma unroll
    for (int n = 0; n < 4; ++n) {
      const int off = (kg * 128 + wn + n * 16 + rr) * 8;
      fbh[n] = *(const bf16x8*)(sBh + off);
      fbl[n] = *(const bf16x8*)(sBl + off);
    }
#pragma unroll
    for (int m = 0; m < 4; ++m)
#pragma unroll
      for (int n = 0; n < 4; ++n) {
        acc[m][n] = __builtin_amdgcn_mfma_f32_16x16x32_bf16(fah[m], fbh[n], acc[m][n], 0, 0, 0);
        acc[m][n] = __builtin_amdgcn_mfma_f32_16x16x32_bf16(fah[m], fbl[n], acc[m][n], 0, 0, 0);
        acc[m][n] = __builtin_amdgcn_mfma_f32_16x16x32_bf16(fal[m], fbh[n], acc[m][n], 0, 0, 0);
      }
    __syncthreads();
  }

  // epilogue: C/D layout col = lane&15, row = (lane>>4)*4 + j
  const int row0 = wm + kg * 4;
  const int Kc2 = N >> 3;
#pragma unroll
  for (int n = 0; n < 4; ++n) {
    const int gcol = nblk * 128 + wn + n * 16 + rr;
    if (EPI == 4) {
      const int sel = gcol >> 10;  // uniform per block (128-col stripe)
      const int lcol = gcol & 1023;
      const float bv = (sel == 0 ? bias : sel == 1 ? bias2 : bias3)[lcol];
      bf16* dh = sel ? Dh2 : Dh;
      bf16* dl = sel ? Dl2 : Dl;
      const size_t tb = ((size_t)(mblk * 128 + (lcol >> 3)) * 128) * 8 + (lcol & 7);
#pragma unroll
      for (int m = 0; m < 4; ++m)
#pragma unroll
        for (int j = 0; j < 4; ++j) {
          const int r = row0 + m * 16 + j;
          float xv = acc[m][n][j] + bv;
          if (sel == 1) xv = (xv > 0.0f) ? xv + 1.0f : expf(xv);
          if (sel == 2) {
            C[(size_t)(mblk * 128 + r) * 1024 + lcol] = xv;
          } else {
            const bf16 h = (bf16)xv;
            dh[tb + (size_t)r * 8] = h;
            dl[tb + (size_t)r * 8] = (bf16)(xv - (float)h);
          }
        }
    } else {
      const float bv = bias ? bias[gcol] : 0.0f;
      const size_t tb = ((size_t)(mblk * Kc2 + (gcol >> 3)) * 128) * 8 + (gcol & 7);
#pragma unroll
      for (int m = 0; m < 4; ++m)
#pragma unroll
        for (int j = 0; j < 4; ++j) {
          const int r = row0 + m * 16 + j;
          float xv = acc[m][n][j] + bv;
          if (EPI == 2) xv = 0.5f * xv * (1.0f + erff(xv * 0.70710678118654752f));
          if (EPI == 3) {
            const int e = (mblk * 128 + r) - gcol - 1;
            xv = (e >= 0) ? xv * powd[e] : 0.0f;
          }
          if (!TOUT) {
            C[(size_t)(mblk * 128 + r) * N + gcol] = xv;
          } else {
            const bf16 h = (bf16)xv;
            Dh[tb + (size_t)r * 8] = h;
            Dl[tb + (size_t)r * 8] = (bf16)(xv - (float)h);
          }
        }
    }
  }
}

// ------- fused residual + partial-sum + bias + LayerNorm; emits fp32 + tiled hi/lo -------
__global__ __launch_bounds__(256) void k_ln(const float* __restrict__ x1,
                                            const float* __restrict__ x2, int nparts,
                                            long long pstride,
                                            const float* __restrict__ bias2,
                                            const float* __restrict__ g,
                                            const float* __restrict__ be,
                                            float* __restrict__ out,
                                            bf16* __restrict__ th, bf16* __restrict__ tl) {
  const int row = blockIdx.x;
  const int t = threadIdx.x;
  const int lane = t & 63;
  const int wave = t >> 6;
  const int cc = t * 4;
  const float4 a = *(const float4*)(x1 + (size_t)row * 1024 + cc);
  float v[4] = {a.x, a.y, a.z, a.w};
  for (int p = 0; p < nparts; ++p) {
    const float4 b = *(const float4*)(x2 + (size_t)p * pstride + (size_t)row * 1024 + cc);
    v[0] += b.x; v[1] += b.y; v[2] += b.z; v[3] += b.w;
  }
  if (bias2) {
    const float4 b = *(const float4*)(bias2 + cc);
    v[0] += b.x; v[1] += b.y; v[2] += b.z; v[3] += b.w;
  }
  __shared__ float red[4];
  float s = v[0] + v[1] + v[2] + v[3];
#pragma unroll
  for (int o = 1; o < 64; o <<= 1) s += __shfl_xor(s, o);
  if (lane == 0) red[wave] = s;
  __syncthreads();
  s = red[0] + red[1] + red[2] + red[3];
  const float mean = s * (1.0f / 1024.0f);
  float q = 0.0f;
#pragma unroll
  for (int j = 0; j < 4; ++j) {
    const float d = v[j] - mean;
    q += d * d;
  }
#pragma unroll
  for (int o = 1; o < 64; o <<= 1) q += __shfl_xor(q, o);
  __syncthreads();
  if (lane == 0) red[wave] = q;
  __syncthreads();
  q = red[0] + red[1] + red[2] + red[3];
  const float rstd = rsqrtf(q * (1.0f / 1024.0f) + 1e-5f);
  float y[4];
#pragma unroll
  for (int j = 0; j < 4; ++j) y[j] = (v[j] - mean) * rstd * g[cc + j] + be[cc + j];
  const float4 o4 = {y[0], y[1], y[2], y[3]};
  *(float4*)(out + (size_t)row * 1024 + cc) = o4;
  const int mblk = row >> 7, r = row & 127, kc = t >> 1, j0 = (t & 1) * 4;
  const size_t off = ((size_t)(mblk * 128 + kc) * 128 + r) * 8 + j0;
  bf16x4 hh, ll;
#pragma unroll
  for (int j = 0; j < 4; ++j) {
    const bf16 hj = (bf16)y[j];
    hh[j] = hj;
    ll[j] = (bf16)(y[j] - (float)hj);
  }
  *(bf16x4*)(th + off) = hh;
  *(bf16x4*)(tl + off) = ll;
}

// ---------------- launch ----------------
extern "C" void kernel_launch(void* const* d_in, const int* in_sizes, int n_in,
                              void* d_out, int out_size, void* d_ws, size_t ws_size,
                              hipStream_t stream) {
  const float* x = (const float*)d_in[0];
  const float* Wq = (const float*)d_in[1];
  const float* bq = (const float*)d_in[2];
  const float* Wk = (const float*)d_in[3];
  const float* bk = (const float*)d_in[4];
  const float* Wv = (const float*)d_in[5];
  const float* bv = (const float*)d_in[6];
  const float* Wo = (const float*)d_in[7];
  const float* bo = (const float*)d_in[8];
  const float* dp = (const float*)d_in[9];
  const float* gf = (const float*)d_in[10];
  const float* bfv = (const float*)d_in[11];
  const float* W1 = (const float*)d_in[12];
  const float* b1 = (const float*)d_in[13];
  const float* W2 = (const float*)d_in[14];
  const float* b2 = (const float*)d_in[15];
  const float* gc = (const float*)d_in[16];
  const float* bc = (const float*)d_in[17];
  const float* Wh = (const float*)d_in[18];
  const float* bh = (const float*)d_in[19];
  float* out = (float*)d_out;

  char* w = (char*)d_ws;
  size_t o = 0;
  auto alloc = [&](size_t bytes) -> void* {
    void* p = w + o;
    o += (bytes + 255) & ~(size_t)255;
    return p;
  };
  const size_t MD = (size_t)4096 * 1024;  // [B*S][D] elements

  // --- persistent region ---
  float* powd = (float*)alloc(2048 * 4);
  float* hf = (float*)alloc(MD * 4);
  float* t1 = (float*)alloc(MD * 4 * 4);  // 4 split-K partials
  float* t2 = (float*)alloc(MD * 4 * 2);  // 2 split-K partials
  bf16* hAh = (bf16*)alloc(MD * 2);
  bf16* hAl = (bf16*)alloc(MD * 2);
  // --- CMS/head tile region (also hosts attention scratch, lifetimes disjoint) ---
  char* sb = (char*)alloc((size_t)(65536 + 32768) * 1024 * 2 * 2);  // BH + AH, hi+lo
  bf16* BHh = (bf16*)sb;
  bf16* BHl = BHh + (size_t)32000 * 1024;
  bf16* AHh = BHl + (size_t)32000 * 1024;
  bf16* AHl = AHh + (size_t)4096 * 4096;
  // attention scratch overlay (all dead before first CMS convB)
  size_t so = 0;
  auto salloc = [&](size_t bytes) -> void* {
    void* p = sb + so;
    so += (bytes + 255) & ~(size_t)255;
    return p;
  };
  bf16* XAh = (bf16*)salloc(MD * 2);
  bf16* XAl = (bf16*)salloc(MD * 2);
  bf16* WQKVh = (bf16*)salloc((size_t)3072 * 1024 * 2);
  bf16* WQKVl = (bf16*)salloc((size_t)3072 * 1024 * 2);
  bf16* Woh = (bf16*)salloc((size_t)1024 * 1024 * 2);
  bf16* Wol = (bf16*)salloc((size_t)1024 * 1024 * 2);
  float* vf = (float*)salloc(MD * 4);
  bf16* vTh = (bf16*)salloc(MD * 2);
  bf16* vTl = (bf16*)salloc(MD * 2);
  bf16* QTh = (bf16*)salloc(MD * 2);
  bf16* QTl = (bf16*)salloc(MD * 2);
  bf16* KTh = (bf16*)salloc(MD * 2);
  bf16* KTl = (bf16*)salloc(MD * 2);
  bf16* SCh = (bf16*)salloc((size_t)2 * 2048 * 2048 * 2);
  bf16* SCl = (bf16*)salloc((size_t)2 * 2048 * 2048 * 2);
  bf16* FAh = (bf16*)salloc(MD * 2);
  bf16* FAl = (bf16*)salloc(MD * 2);

  const long long SD = 2048LL * 1024;
  const long long SS = 2048LL * 2048;
  const long long PD = 4096LL * 1024;  // partial stride
  const size_t SL = (size_t)1024 * 1024;  // one weight slice in WQKV tiles
  float* nf = nullptr;
  bf16* nb = nullptr;

  k_pow<<<8, 256, 0, stream>>>(dp, powd);

  // --- merged qkv projection ---
  k_convA<<<dim3(16, 32), 256, 0, stream>>>(x, XAh, XAl, 1024);
  k_convB<<<dim3(16, 8), 256, 0, stream>>>(Wq, WQKVh, WQKVl, 1024, 1024, 0, 0);
  k_convB<<<dim3(16, 8), 256, 0, stream>>>(Wk, WQKVh + SL, WQKVl + SL, 1024, 1024, 0, 0);
  k_convB<<<dim3(16, 8), 256, 0, stream>>>(Wv, WQKVh + 2 * SL, WQKVl + 2 * SL, 1024, 1024, 0, 0);
  k_convB<<<dim3(16, 8), 256, 0, stream>>>(Wo, Woh, Wol, 1024, 1024, 0, 0);
  k_gemm<4, false, false><<<dim3(32, 24), 256, 0, stream>>>(
      XAh, XAl, WQKVh, WQKVl, vf, QTh, QTl, KTh, KTl, bq, bk, bv, nullptr,
      3072, 1024, 0, 0, 0, 0);
  k_convB<<<dim3(32, 8, 2), 256, 0, stream>>>(vf, vTh, vTl, 2048, 1024, SD, SD);

  // --- decayed linear attention ---
  k_gemm<3, true, false><<<dim3(16, 16, 2), 256, 0, stream>>>(
      QTh, QTl, KTh, KTl, nf, SCh, SCl, nb, nb, nullptr, nullptr, nullptr, powd,
      2048, 1024, 0, SD, SD, SS);
  k_gemm<0, true, false><<<dim3(16, 8, 2), 256, 0, stream>>>(
      SCh, SCl, vTh, vTl, nf, FAh, FAl, nb, nb, nullptr, nullptr, nullptr, nullptr,
      1024, 2048, 4, SS, SD, SD);
  k_gemm<0, false, true><<<dim3(32, 8, 2), 256, 0, stream>>>(
      FAh, FAl, Woh, Wol, t2, nb, nb, nb, nb, nullptr, nullptr, nullptr, nullptr,
      1024, 1024, 0, 0, 0, PD);
  k_ln<<<4096, 256, 0, stream>>>(x, t2, 2, PD, bo, gf, bfv, hf, hAh, hAl);

  // --- CMS stack ---
  for (int l = 0; l < 4; ++l) {
    k_convB<<<dim3(16, 32), 256, 0, stream>>>(W1 + (size_t)l * 1024 * 4096, BHh, BHl,
                                              1024, 4096, 0, 0);
    k_gemm<2, true, false><<<dim3(32, 32), 256, 0, stream>>>(
        hAh, hAl, BHh, BHl, nf, AHh, AHl, nb, nb, b1 + l * 4096, nullptr, nullptr,
        nullptr, 4096, 1024, 0, 0, 0, 0);
    k_convB<<<dim3(64, 8), 256, 0, stream>>>(W2 + (size_t)l * 4096 * 1024, BHh, BHl,
                                             4096, 1024, 0, 0);
    k_gemm<0, false, true><<<dim3(32, 8, 4), 256, 0, stream>>>(
        AHh, AHl, BHh, BHl, t1, nb, nb, nb, nb, nullptr, nullptr, nullptr, nullptr,
        1024, 4096, 0, 0, 0, PD);
    k_ln<<<4096, 256, 0, stream>>>(hf, t1, 4, PD, b2 + l * 1024, gc + l * 1024,
                                   bc + l * 1024, hf, hAh, hAl);
  }

  // --- LM head ---
  k_convB<<<dim3(16, 250), 256, 0, stream>>>(Wh, BHh, BHl, 1024, 32000, 0, 0);
  k_gemm<0, false, false><<<dim3(32, 250), 256, 0, stream>>>(
      hAh, hAl, BHh, BHl, out, nb, nb, nb, nb, bh, nullptr, nullptr, nullptr,
      32000, 1024, 0, 0, 0, 0);
}